// Round 1
// baseline (349.936 us; speedup 1.0000x reference)
//
#include <hip/hip_runtime.h>
#include <hip/hip_bf16.h>
#include <stdint.h>

#define DEVI static __device__ __forceinline__

typedef __attribute__((ext_vector_type(4))) float f32x4;
typedef __attribute__((ext_vector_type(8))) short bf16x8;
typedef unsigned short u16;
typedef unsigned int u32;

// B=16, N=4096, C=384, H=8, D=48
#define BB 16
#define NN 4096
#define CC 384
#define HH 8
#define DD 48

DEVI u16 f2bf(float f) {
  union { float f; u32 u; } c; c.f = f;
  u32 u = c.u;
  u32 r = (u + 0x7FFFu + ((u >> 16) & 1u)) >> 16;
  return (u16)r;
}
DEVI float bf2f(u16 h) {
  union { float f; u32 u; } c; c.u = ((u32)h) << 16;
  return c.f;
}

// ---- staging helpers: read 8 K-contiguous elems, write 8 bf16 (16B) to LDS ----
DEVI void stage8(u16* dst, const float* src) {
  const f32x4 a = *(const f32x4*)(src);
  const f32x4 b = *(const f32x4*)(src + 4);
  union { bf16x8 v; u16 u[8]; } o;
  o.u[0] = f2bf(a[0]); o.u[1] = f2bf(a[1]); o.u[2] = f2bf(a[2]); o.u[3] = f2bf(a[3]);
  o.u[4] = f2bf(b[0]); o.u[5] = f2bf(b[1]); o.u[6] = f2bf(b[2]); o.u[7] = f2bf(b[3]);
  *(bf16x8*)dst = o.v;
}
DEVI void stage8(u16* dst, const u16* src) {
  *(bf16x8*)dst = *(const bf16x8*)src;
}
DEVI void store_out(float* p, float v) { *p = v; }
DEVI void store_out(u16* p, float v) { *p = f2bf(v); }

// ============================================================================
// Fused-weight precompute:  W'[o][c] = sum_m wtop[o][m]*cw[m][c]
//                           b'[o]    = btop[o] + sum_m wtop[o][m]*cb[m]
// o<384 -> wq/bq ; o>=384 -> wkv/bkv.  339 MFLOP, trivial.
// ============================================================================
__global__ __launch_bounds__(384)
void fuse_weights(const float* __restrict__ cw, const float* __restrict__ cb,
                  const float* __restrict__ wq, const float* __restrict__ bq,
                  const float* __restrict__ wkv, const float* __restrict__ bkv,
                  u16* __restrict__ Wf, float* __restrict__ bf_) {
  const int o = blockIdx.x;                 // 0..1151
  const float* wrow;
  float bo;
  if (o < CC) { wrow = wq + (size_t)o * CC;          bo = bq[o]; }
  else        { wrow = wkv + (size_t)(o - CC) * CC;  bo = bkv[o - CC]; }
  const int c = threadIdx.x;                // 0..383
  float acc = 0.f;
  for (int m = 0; m < CC; ++m) acc += wrow[m] * cw[(size_t)m * CC + c];
  Wf[(size_t)o * CC + c] = f2bf(acc);
  if (c == 0) {
    float s = bo;
    for (int m = 0; m < CC; ++m) s += wrow[m] * cb[m];
    bf_[o] = s;
  }
}

// ============================================================================
// GEMM: C[M,N] = A[M,K] @ W[N,K]^T + bias[N]   (fp32 accumulate, bf16 MFMA)
// BM=128, BN=128, BK=32, 256 threads = 4 waves (2x2), each wave 64x64 (4x4 frags)
// ============================================================================
template<typename AT, typename WT, typename OT>
__global__ __launch_bounds__(256)
void gemm_bt(const AT* __restrict__ A, const WT* __restrict__ W,
             const float* __restrict__ bias, OT* __restrict__ C,
             int M, int N, int K) {
  constexpr int BM = 128, BN = 128, BK = 32, BKp = 40;   // pad: 80B row stride
  __shared__ __align__(16) u16 As[BM * BKp];
  __shared__ __align__(16) u16 Bs[BN * BKp];

  const int bn = blockIdx.x, bm = blockIdx.y;  // bn fastest -> L2/L3 reuse of A tile
  const int t = threadIdx.x;
  const int wid = t >> 6, lane = t & 63;
  const int wr = wid >> 1, wc = wid & 1;
  const int row0 = bm * BM, col0 = bn * BN;
  const int lrow = lane & 15, lk = (lane >> 4) * 8;

  f32x4 acc[4][4] = {};

  for (int k0 = 0; k0 < K; k0 += BK) {
    __syncthreads();
#pragma unroll
    for (int it = 0; it < 2; ++it) {
      const int idx = it * 256 + t;        // 0..511
      const int r = idx >> 2, c8 = (idx & 3) * 8;
      stage8(&As[r * BKp + c8], A + (size_t)(row0 + r) * K + k0 + c8);
      stage8(&Bs[r * BKp + c8], W + (size_t)(col0 + r) * K + k0 + c8);
    }
    __syncthreads();
    bf16x8 af[4], bf[4];
#pragma unroll
    for (int i = 0; i < 4; ++i)
      af[i] = *(const bf16x8*)&As[(wr * 64 + i * 16 + lrow) * BKp + lk];
#pragma unroll
    for (int j = 0; j < 4; ++j)
      bf[j] = *(const bf16x8*)&Bs[(wc * 64 + j * 16 + lrow) * BKp + lk];
#pragma unroll
    for (int i = 0; i < 4; ++i)
#pragma unroll
      for (int j = 0; j < 4; ++j)
        acc[i][j] = __builtin_amdgcn_mfma_f32_16x16x32_bf16(af[i], bf[j], acc[i][j], 0, 0, 0);
  }

  // epilogue: C/D layout col = lane&15, row = (lane>>4)*4 + reg
  const int orow = row0 + wr * 64, ocol = col0 + wc * 64;
  const int lr = (lane >> 4) * 4;
#pragma unroll
  for (int i = 0; i < 4; ++i)
#pragma unroll
    for (int j = 0; j < 4; ++j) {
      const int cccol = ocol + j * 16 + lrow;
      const float bv = bias[cccol];
#pragma unroll
      for (int r = 0; r < 4; ++r) {
        const int rr = orow + i * 16 + lr + r;
        store_out(&C[(size_t)rr * N + cccol], acc[i][j][r] + bv);
      }
    }
}

// ============================================================================
// Gram + softmax: S[bh][i][j] = scale * sum_n q[n][i]*k[n][j]  (K = n = 4096)
// attn = softmax_j(S).  One block per (b,h); 4 waves each own 16 n-chunks of 64,
// LDS-transpose staging (n-dim is row-strided in qkv), 3x3 MFMA tiles,
// cross-wave partial reduce in LDS (aliased onto dead staging buffers).
// ============================================================================
__global__ __launch_bounds__(256)
void gram_softmax(const u16* __restrict__ qkv, float* __restrict__ attn) {
  __shared__ __align__(16) char smem[4 * 2 * 48 * 72 * 2];   // 55296 B
  const int bh = blockIdx.x, b = bh >> 3, h = bh & 7;
  const int t = threadIdx.x, wid = t >> 6, lane = t & 63;
  u16* qt = (u16*)smem + (size_t)(wid * 2 + 0) * (48 * 72);
  u16* kt = (u16*)smem + (size_t)(wid * 2 + 1) * (48 * 72);
  const int lrow = lane & 15, lk = (lane >> 4) * 8;

  f32x4 acc[3][3] = {};
  for (int ch = wid * 16; ch < wid * 16 + 16; ++ch) {
    const int n0 = ch * 64;
    // stage q,k slices transposed: qt[i][nn] = qkv[b, n0+nn, h*48+i]
#pragma unroll
    for (int r = 0; r < 24; ++r) {
      const int e = r * 64 + lane;               // 0..1535
      const int nn = e / 24, i2 = e % 24;
      const size_t base = (size_t)(b * NN + n0 + nn) * (3 * CC) + h * DD + i2 * 2;
      const u32 qv = *(const u32*)(qkv + base);
      qt[(i2 * 2 + 0) * 72 + nn] = (u16)(qv & 0xffffu);
      qt[(i2 * 2 + 1) * 72 + nn] = (u16)(qv >> 16);
      const u32 kv = *(const u32*)(qkv + base + CC);
      kt[(i2 * 2 + 0) * 72 + nn] = (u16)(kv & 0xffffu);
      kt[(i2 * 2 + 1) * 72 + nn] = (u16)(kv >> 16);
    }
    // per-wave staging: compiler inserts lgkmcnt waits for the LDS dep
#pragma unroll
    for (int kk = 0; kk < 2; ++kk) {
      bf16x8 af[3], bf[3];
#pragma unroll
      for (int i = 0; i < 3; ++i)
        af[i] = *(const bf16x8*)&qt[(i * 16 + lrow) * 72 + kk * 32 + lk];
#pragma unroll
      for (int j = 0; j < 3; ++j)
        bf[j] = *(const bf16x8*)&kt[(j * 16 + lrow) * 72 + kk * 32 + lk];
#pragma unroll
      for (int i = 0; i < 3; ++i)
#pragma unroll
        for (int j = 0; j < 3; ++j)
          acc[i][j] = __builtin_amdgcn_mfma_f32_16x16x32_bf16(af[i], bf[j], acc[i][j], 0, 0, 0);
    }
  }
  __syncthreads();                  // staging buffers dead; alias partial-S
  float* Sp = (float*)smem;         // [4][48*48] = 36864 B
  const int lr = (lane >> 4) * 4;
#pragma unroll
  for (int i = 0; i < 3; ++i)
#pragma unroll
    for (int j = 0; j < 3; ++j)
#pragma unroll
      for (int r = 0; r < 4; ++r)
        Sp[wid * 2304 + (i * 16 + lr + r) * 48 + (j * 16 + lrow)] = acc[i][j][r];
  __syncthreads();
  if (t < 48) {                     // one thread per row: reduce + softmax
    float mx = -1e30f;
    for (int j = 0; j < 48; ++j) {
      float v = (Sp[t * 48 + j] + Sp[2304 + t * 48 + j] +
                 Sp[4608 + t * 48 + j] + Sp[6912 + t * 48 + j]) * 0.015625f; // N^-0.5
      Sp[t * 48 + j] = v;
      mx = fmaxf(mx, v);
    }
    float sum = 0.f;
    for (int j = 0; j < 48; ++j) {
      const float e = __expf(Sp[t * 48 + j] - mx);
      Sp[t * 48 + j] = e;
      sum += e;
    }
    const float inv = 1.f / sum;
    for (int j = 0; j < 48; ++j)
      attn[((size_t)bh * 48 + t) * 48 + j] = Sp[t * 48 + j] * inv;
  }
}

// ============================================================================
// PV: R[b,i,h,n] = sum_j attn[bh][i][j] * v[b,n,j]   (v = qkv cols 768+h*48+j)
// R's "verbatim torch reshape" layout == natural dense [b][i][h][n].
// Block = (b,h, 64-token chunk); MFMA A=attn(48x64 zero-pad), B-frag straight
// from v rows (j contiguous). Each wave handles 16 tokens.
// ============================================================================
__global__ __launch_bounds__(256)
void pv_kernel(const u16* __restrict__ qkv, const float* __restrict__ attn,
               u16* __restrict__ R) {
  const int blk = blockIdx.x;            // 128 * 64
  const int bh = blk >> 6, nc = blk & 63;
  const int b = bh >> 3, h = bh & 7;
  const int t = threadIdx.x, wid = t >> 6, lane = t & 63;

  __shared__ __align__(16) u16 Albs[48 * 72];   // attn bf16, cols 48..63 zero
  __shared__ __align__(16) u16 Vlds[64 * 72];   // v tokens,   cols 48..63 zero

#pragma unroll
  for (int r = 0; r < 12; ++r) {
    const int e = r * 256 + t;          // 0..3071 : 48 x 64
    const int i = e >> 6, j = e & 63;
    const float a = (j < 48) ? attn[((size_t)bh * 48 + i) * 48 + j] : 0.0f;
    Albs[i * 72 + j] = f2bf(a);
  }
  const int n0 = nc * 64;
#pragma unroll
  for (int r = 0; r < 16; ++r) {
    const int e = r * 256 + t;          // 0..4095 : 64 x 64
    const int nn = e >> 6, j = e & 63;
    u16 v = 0;
    if (j < 48) v = qkv[(size_t)(b * NN + n0 + nn) * (3 * CC) + 2 * CC + h * DD + j];
    Vlds[nn * 72 + j] = v;
  }
  __syncthreads();

  const int lrow = lane & 15, lk = (lane >> 4) * 8;
  f32x4 acc[3] = {};
#pragma unroll
  for (int kk = 0; kk < 2; ++kk) {
    const bf16x8 bfrag = *(const bf16x8*)&Vlds[(wid * 16 + lrow) * 72 + kk * 32 + lk];
#pragma unroll
    for (int i = 0; i < 3; ++i) {
      const bf16x8 afrag = *(const bf16x8*)&Albs[(i * 16 + lrow) * 72 + kk * 32 + lk];
      acc[i] = __builtin_amdgcn_mfma_f32_16x16x32_bf16(afrag, bfrag, acc[i], 0, 0, 0);
    }
  }
  const int lr = (lane >> 4) * 4;
  const int n = n0 + wid * 16 + lrow;
#pragma unroll
  for (int i = 0; i < 3; ++i)
#pragma unroll
    for (int r = 0; r < 4; ++r) {
      const int ii = i * 16 + lr + r;
      R[(((size_t)b * DD + ii) * HH + h) * NN + n] = f2bf(acc[i][r]);
    }
}

// ============================================================================
extern "C" void kernel_launch(void* const* d_in, const int* in_sizes, int n_in,
                              void* d_out, int out_size, void* d_ws, size_t ws_size,
                              hipStream_t stream) {
  const float* x      = (const float*)d_in[0];
  const float* conv_w = (const float*)d_in[1];
  const float* conv_b = (const float*)d_in[2];
  const float* wq     = (const float*)d_in[3];
  const float* bq     = (const float*)d_in[4];
  const float* wkv    = (const float*)d_in[5];
  const float* bkv    = (const float*)d_in[6];
  const float* wp     = (const float*)d_in[7];
  const float* bp     = (const float*)d_in[8];
  float* y = (float*)d_out;

  char* ws = (char*)d_ws;
  u16*   Wf   = (u16*)ws;                                  //  884,736 B
  float* bf_  = (float*)(ws + 884736);                     //    4,608 B
  float* attn = (float*)(ws + 889344);                     // 1,179,648 B
  u16*   qkv  = (u16*)(ws + 2068992);                      // 150,994,944 B
  u16*   R    = (u16*)(ws + 2068992 + 150994944);          // 50,331,648 B
  // total ws use: 203,395,584 B

  fuse_weights<<<dim3(3 * CC), dim3(CC), 0, stream>>>(conv_w, conv_b, wq, bq,
                                                      wkv, bkv, Wf, bf_);
  // qkv = x @ Wf^T + bf : M=65536, N=1152, K=384
  gemm_bt<float, u16, u16><<<dim3(9, 512), dim3(256), 0, stream>>>(
      x, Wf, bf_, qkv, BB * NN, 3 * CC, CC);
  gram_softmax<<<dim3(BB * HH), dim3(256), 0, stream>>>(qkv, attn);
  pv_kernel<<<dim3(BB * HH * (NN / 64)), dim3(256), 0, stream>>>(qkv, attn, R);
  // y = R @ wp^T + bp : M=65536, N=384, K=384
  gemm_bt<u16, float, float><<<dim3(3, 512), dim3(256), 0, stream>>>(
      R, wp, bp, y, BB * NN, CC, CC);
}